// Round 12
// baseline (161.943 us; speedup 1.0000x reference)
//
#include <hip/hip_runtime.h>

// BSScanThru: out = brev8( (brev8(a) + brev8(b) + carry-chain) mod 256 ) & ~b
//
// Wave-decoupled single pass, 4 chained sub-tiles per wave, software-
// pipelined loads. NO __syncthreads, NO LDS, no inter-wave communication.
//
// Carry-lookahead identity: p_j = (c_j == 255) implies g_j = 0, so the
// carry into any position equals g of the NEAREST preceding element with
// c != 255. Each wave owns 4096 consecutive elems (4 sub-tiles of 1024)
// and peeks backward ONCE from its span base (64-elem coalesced window,
// ballot c != 255, g of highest lane; step back on all-propagate, prob
// ~2^-512; idx<0 acts as {c=0,g=0} so array start needs no special case).
//
// Within the wave, carry state chains across sub-tiles IN REGISTER:
// carry-out of the 64-bit ballot-adder chain (Gw + (Gw|Pw) + cb) is
// exactly the next sub-tile's carry-in (g,p disjoint => adder carry
// chain == gp recurrence; carry into bit k = P_k ^ S_k).
//   thread level (16 elems): Cm = P ^ (G + (G|P) + c_t)
//   wave level  (64 thr)  : c_t = bit lane of Pw ^ (Gw + (Gw|Pw) + cb)
//
// Software pipeline: sub-tile t+1's loads are issued (into the other
// register buffer, statically indexed) before sub-tile t's compute, so
// 2 sub-tiles of dwordx4 loads stay in flight continuously instead of
// draining vmcnt(0) at every 1024-elem boundary.
//
// Geometry: EPT=16 (64 B/lane — r10: 128 B/lane span cost +23% FETCH).
// No XCD swizzle (r8: broke natural L3 locality). No nontemporal stores
// (r7: WRITE +66%). Occupancy >60% buys nothing (r9).
//
// Inputs: int32 (values 0..255). Output: int32.

#define BLK 256
#define EPT 16
#define WSUB (64 * EPT)      // 1024 elems per sub-tile
#define KSUB 4               // chained sub-tiles per wave
#define WSPAN (WSUB * KSUB)  // 4096 elems per wave
#define WAVES (BLK / 64)

typedef int iv4 __attribute__((ext_vector_type(4)));

__device__ __forceinline__ unsigned brev8(unsigned x) {
    return __brev(x) >> 24;
}

__device__ __forceinline__ void load_sub(const int* __restrict__ a,
                                         const int* __restrict__ b,
                                         int base, iv4* av, iv4* bv) {
#pragma unroll
    for (int q = 0; q < 4; ++q) {
        av[q] = *reinterpret_cast<const iv4*>(a + base + q * 4);
        bv[q] = *reinterpret_cast<const iv4*>(b + base + q * 4);
    }
}

// Compute one 1024-elem sub-tile from registers; store; return wave carry-out.
__device__ __forceinline__ unsigned comp_sub(const iv4* av, const iv4* bv,
                                             int base, int lane, unsigned cb,
                                             int* __restrict__ out) {
    const int* ae = reinterpret_cast<const int*>(av);
    const int* be = reinterpret_cast<const int*>(bv);
    unsigned c[EPT], G = 0u, P = 0u;
#pragma unroll
    for (int k = 0; k < EPT; ++k) {
        unsigned s = brev8((unsigned)ae[k]) + brev8((unsigned)be[k]);
        c[k] = s & 0xFFu;
        G |= (s >> 8) << k;               // carry generated
        P |= ((c[k] + 1u) >> 8) << k;     // 1 iff c[k]==255
    }
    const unsigned GoP = G | P;
    const unsigned g_t = (G + GoP) >> EPT;           // 16-elem carry-out (cin=0)
    const unsigned p_t = (P == 0xFFFFu) ? 1u : 0u;

    const unsigned long long Gw = __ballot(g_t != 0u);
    const unsigned long long Pw = __ballot(p_t != 0u);
    const unsigned long long T  = Gw + (Gw | Pw);
    const unsigned long long Sw = T + (unsigned long long)cb;
    const unsigned cout = (unsigned)((T < Gw) | (Sw < T));   // wave carry-out
    const unsigned c_t  = (unsigned)(((Pw ^ Sw) >> lane) & 1ull);
    const unsigned Cm = P ^ (G + GoP + c_t);

    iv4 o[4];
    int* of = reinterpret_cast<int*>(o);
#pragma unroll
    for (int k = 0; k < EPT; ++k) {
        unsigned res = (c[k] + ((Cm >> k) & 1u)) & 0xFFu;
        of[k] = (int)(brev8(res) & (~(unsigned)be[k] & 0xFFu));
    }
#pragma unroll
    for (int q = 0; q < 4; ++q)
        *reinterpret_cast<iv4*>(out + base + q * 4) = o[q];
    return cout;
}

__global__ __launch_bounds__(BLK) void bss_wave(const int* __restrict__ a,
                                                const int* __restrict__ b,
                                                int* __restrict__ out) {
    const int tid = threadIdx.x;
    const int lane = tid & 63;
    const int wid = tid >> 6;
    const long w0 = ((long)blockIdx.x * WAVES + wid) * WSPAN;  // wave span base
    const int sb = (int)w0 + lane * EPT;

    // ---- prime the pipeline: 2 sub-tiles of loads in flight ----
    iv4 avA[4], bvA[4], avB[4], bvB[4];
    load_sub(a, b, sb,        avA, bvA);
    load_sub(a, b, sb + WSUB, avB, bvB);

    // ---- wave carry-in via backward peek (once per 4096 elems) ----
    unsigned cb = 0u;
    {
        long w = w0 - 64;
        for (;;) {
            long idx = w + lane;
            unsigned cc = 0u, gg = 0u;   // idx < 0: virtual non-propagating, g=0
            if (idx >= 0) {
                unsigned s = brev8((unsigned)a[idx]) + brev8((unsigned)b[idx]);
                cc = s & 0xFFu;
                gg = s >> 8;
            }
            unsigned long long m = __ballot(cc != 0xFFu);
            if (m) {
                int hi = 63 - __clzll(m);        // nearest to span base
                cb = (unsigned)__shfl((int)gg, hi, 64);
                break;
            }
            w -= 64;
        }
    }

    // ---- chained, pipelined sub-tiles (all indices static) ----
    cb = comp_sub(avA, bvA, sb,            lane, cb, out);
    load_sub(a, b, sb + 2 * WSUB, avA, bvA);
    cb = comp_sub(avB, bvB, sb + WSUB,     lane, cb, out);
    load_sub(a, b, sb + 3 * WSUB, avB, bvB);
    cb = comp_sub(avA, bvA, sb + 2 * WSUB, lane, cb, out);
    (void)comp_sub(avB, bvB, sb + 3 * WSUB, lane, cb, out);
}

extern "C" void kernel_launch(void* const* d_in, const int* in_sizes, int n_in,
                              void* d_out, int out_size, void* d_ws, size_t ws_size,
                              hipStream_t stream) {
    const int* a = (const int*)d_in[0];
    const int* b = (const int*)d_in[1];
    int* out = (int*)d_out;
    const int n = in_sizes[0];                 // 67108864
    const int nblk = n / (WSPAN * WAVES);      // 4096 blocks

    bss_wave<<<nblk, BLK, 0, stream>>>(a, b, out);
}

// Round 13
// 144.290 us; speedup vs baseline: 1.1223x; 1.1223x over previous
//
#include <hip/hip_runtime.h>

// BSScanThru: out = brev8( (brev8(a) + brev8(b) + carry-chain) mod 256 ) & ~b
//
// Wave-decoupled single pass with PERFECTLY-COALESCED accesses.
//
// Round-13 change (request-rate theory): previous variants had lane
// stride 64B within each load instruction -> 64 lines touched per instr,
// 16B used per line -> 4x the TA/L1 line-lookup rate of a contiguous
// pattern. This round: wave tile (1024 elems) split into 4 chunks of
// 256; in chunk q, lane l owns elems q*256 + l*4 .. +3, so every
// load/store instruction is 64 lanes x 16B contiguous = 16 fully-used
// lines. Bytes unchanged; requests/byte cut 4x.
//
// Carry-lookahead identity: p_j = (c_j==255) implies g_j = 0, so carry
// into any position = g of the nearest preceding element with c != 255.
// Each wave peeks backward once from its tile base (64-elem window,
// ballot c!=255, g of highest lane; step back on all-propagate, prob
// ~2^-512; idx<0 acts as {c=0,g=0} -> array start needs no special case).
//
// Adder trick (g,p disjoint => carry chain of G+(G|P)+cin IS the gp
// recurrence; carry into bit k = P_k ^ S_k):
//   4-elem group:  Cm = P ^ (G + (G|P) + c_t)      (4-bit masks)
//   wave chunk:    c_t = bit lane of Pw ^ (Gw + (Gw|Pw) + cb)
//   chunk chain:   cb' = carry-out of the 64-bit add (in-register).
//
// No XCD swizzle (r8: broke L3 locality). No nontemporal stores (r7:
// WRITE +66%). No LDS/barriers (r11: neutral, keeps it simple).
//
// Inputs: int32 (values 0..255). Output: int32.

#define BLK 256
#define CHUNK 256            // elems per chunk: 64 lanes x 4
#define NCHUNK 4
#define WTILE (CHUNK * NCHUNK)  // 1024 elems per wave
#define WAVES (BLK / 64)

typedef int iv4 __attribute__((ext_vector_type(4)));

__device__ __forceinline__ unsigned brev8(unsigned x) {
    return __brev(x) >> 24;
}

__global__ __launch_bounds__(BLK) void bss_coal(const int* __restrict__ a,
                                                const int* __restrict__ b,
                                                int* __restrict__ out) {
    const int tid = threadIdx.x;
    const int lane = tid & 63;
    const int wid = tid >> 6;
    const long w0 = ((long)blockIdx.x * WAVES + wid) * WTILE;  // wave tile base

    // ---- main tile loads issued FIRST: 8 perfectly-contiguous dwordx4 ----
    iv4 av[NCHUNK], bv[NCHUNK];
#pragma unroll
    for (int q = 0; q < NCHUNK; ++q) {
        const int off = (int)w0 + q * CHUNK + lane * 4;
        av[q] = *reinterpret_cast<const iv4*>(a + off);
        bv[q] = *reinterpret_cast<const iv4*>(b + off);
    }

    // ---- wave carry-in via backward peek ----
    unsigned cb = 0u;
    {
        long w = w0 - 64;
        for (;;) {
            long idx = w + lane;
            unsigned cc = 0u, gg = 0u;   // idx < 0: virtual non-propagating, g=0
            if (idx >= 0) {
                unsigned s = brev8((unsigned)a[idx]) + brev8((unsigned)b[idx]);
                cc = s & 0xFFu;
                gg = s >> 8;
            }
            unsigned long long m = __ballot(cc != 0xFFu);
            if (m) {
                int hi = 63 - __clzll(m);        // nearest to tile base
                cb = (unsigned)__shfl((int)gg, hi, 64);
                break;
            }
            w -= 64;
        }
    }

    // ---- 4 chunks, carry chained in-register across ballot-adder chains ----
#pragma unroll
    for (int q = 0; q < NCHUNK; ++q) {
        unsigned c[4], G = 0u, P = 0u;
#pragma unroll
        for (int j = 0; j < 4; ++j) {
            unsigned s = brev8((unsigned)av[q][j]) + brev8((unsigned)bv[q][j]);
            c[j] = s & 0xFFu;
            G |= (s >> 8) << j;               // carry generated
            P |= ((c[j] + 1u) >> 8) << j;     // 1 iff c[j]==255
        }
        const unsigned GoP = G | P;
        const unsigned g_t = (G + GoP) >> 4;            // 4-elem carry-out (cin=0)
        const unsigned p_t = (P == 0xFu) ? 1u : 0u;

        const unsigned long long Gw = __ballot(g_t != 0u);
        const unsigned long long Pw = __ballot(p_t != 0u);
        const unsigned long long T  = Gw + (Gw | Pw);
        const unsigned long long Sw = T + (unsigned long long)cb;
        const unsigned cout = (unsigned)((T < Gw) | (Sw < T));  // chunk carry-out
        const unsigned c_t  = (unsigned)(((Pw ^ Sw) >> lane) & 1ull);
        const unsigned Cm = P ^ (G + GoP + c_t);

        iv4 o;
#pragma unroll
        for (int j = 0; j < 4; ++j) {
            unsigned res = (c[j] + ((Cm >> j) & 1u)) & 0xFFu;
            o[j] = (int)(brev8(res) & (~(unsigned)bv[q][j] & 0xFFu));
        }
        *reinterpret_cast<iv4*>(out + (int)w0 + q * CHUNK + lane * 4) = o;
        cb = cout;
    }
}

extern "C" void kernel_launch(void* const* d_in, const int* in_sizes, int n_in,
                              void* d_out, int out_size, void* d_ws, size_t ws_size,
                              hipStream_t stream) {
    const int* a = (const int*)d_in[0];
    const int* b = (const int*)d_in[1];
    int* out = (int*)d_out;
    const int n = in_sizes[0];                // 67108864
    const int nblk = n / (WTILE * WAVES);     // 16384 blocks

    bss_coal<<<nblk, BLK, 0, stream>>>(a, b, out);
}